// Round 14
// baseline (48925.839 us; speedup 1.0000x reference)
//
#include <hip/hip_runtime.h>
#include <stdint.h>

typedef unsigned int uint32;
typedef unsigned long long uint64;

#define T_SEQ 8192
#define DLAG  132            // L1 step s runs at node t = s + DLAG (DLAG > K=128)

// ---------------- ws layout (~34MB; 67.1MB proven usable in R2) ----------------
#define WO_WHH0  0ull          // [4096][1024] bf16
#define WO_WIH0  8388608ull    // [4096][304]  bf16
#define WO_WHH1  10878976ull   // [4096][1024] bf16
#define WO_WIH1  19267584ull   // [4096][1024] bf16 (read by GEMM nodes only)
#define WO_B0    27656192ull   // [4096] f32
#define WO_B1    27672576ull   // [4096] f32
#define WO_H1R   27688960ull   // [512][1024] f32 h1 ring (2MB)
#define WO_Z1R   29786112ull   // [2][128][4096] f32 z1 chunk ring (4MB)
#define WO_H2    33980416ull   // [2][1024] f32 (parity s&1)
#define WO_CST0  33988608ull   // [1024] f32
#define WO_CST1  33992704ull   // [1024] f32
#define WO_Y0    33996800ull   // [512] f32
#define WO_Y1    33998848ull   // [512] f32

// ---------------- helpers ----------------
__device__ __forceinline__ float bflo(uint32 u){ return __uint_as_float(u << 16); }
__device__ __forceinline__ float bfhi(uint32 u){ return __uint_as_float(u & 0xffff0000u); }

__device__ __forceinline__ unsigned short f2bf(float f){
  uint32 u = __float_as_uint(f);
  u += 0x7fffu + ((u >> 16) & 1u);          // round-to-nearest-even
  return (unsigned short)(u >> 16);
}

__device__ __forceinline__ void mac8(float& a, uint4 w,
    float h0,float h1,float h2,float h3,float h4,float h5,float h6,float h7){
  a = fmaf(bflo(w.x), h0, a); a = fmaf(bfhi(w.x), h1, a);
  a = fmaf(bflo(w.y), h2, a); a = fmaf(bfhi(w.y), h3, a);
  a = fmaf(bflo(w.z), h4, a); a = fmaf(bfhi(w.z), h5, a);
  a = fmaf(bflo(w.w), h6, a); a = fmaf(bfhi(w.w), h7, a);
}

// ---------------- one-time per call: weights fp32 -> bf16 + bias sums ----------------
extern "C" __global__ void __launch_bounds__(256)
prep_weights(const float* __restrict__ Wih0, const float* __restrict__ Whh0,
             const float* __restrict__ bih0, const float* __restrict__ bhh0,
             const float* __restrict__ Wih1, const float* __restrict__ Whh1,
             const float* __restrict__ bih1, const float* __restrict__ bhh1,
             char* __restrict__ ws)
{
  unsigned short* whh0b = (unsigned short*)(ws + WO_WHH0);
  unsigned short* wih0b = (unsigned short*)(ws + WO_WIH0);
  unsigned short* whh1b = (unsigned short*)(ws + WO_WHH1);
  unsigned short* wih1b = (unsigned short*)(ws + WO_WIH1);
  float* b0 = (float*)(ws + WO_B0);
  float* b1 = (float*)(ws + WO_B1);

  const int stride = gridDim.x * blockDim.x;
  const int tid0 = blockIdx.x * blockDim.x + threadIdx.x;

  for (int i = tid0; i < 4096*1024; i += stride) whh0b[i] = f2bf(Whh0[i]);
  for (int i = tid0; i < 4096*1024; i += stride) whh1b[i] = f2bf(Whh1[i]);
  for (int i = tid0; i < 4096*1024; i += stride) wih1b[i] = f2bf(Wih1[i]);
  for (int i = tid0; i < 4096*304;  i += stride) {
    int r = i / 304, x = i - r * 304;
    wih0b[i] = f2bf(x < 300 ? Wih0[(size_t)r * 300 + x] : 0.0f);
  }
  for (int i = tid0; i < 4096; i += stride) {
    b0[i] = bih0[i] + bhh0[i];
    b1[i] = bih1[i] + bhh1[i];
  }
}

// ---------------- chunk GEMM node: z1[s] = Wih1_bf16 * h1[s], s in chunk c ----------------
// 512 blocks x 256 thr. Block b owns rows b*8..+8; wave wv owns 2 rows (weights in
// 16 VGPRs, loaded once); loops the 128 steps of chunk c. Same per-lane mac order +
// butterfly as the step kernel's old phase-B (numerics class proven in R13).
extern "C" __global__ void __launch_bounds__(256)
gemm_z1(int c, char* __restrict__ ws)
{
  const unsigned short* wih1b = (const unsigned short*)(ws + WO_WIH1);
  const float* h1r = (const float*)(ws + WO_H1R);
  float* z1r = (float*)(ws + WO_Z1R);

  const int tid = threadIdx.x;
  const int wv  = tid >> 6;
  const int cc  = tid & 63;
  const int row0 = (int)blockIdx.x * 8 + wv * 2;

  const uint4* wpA = (const uint4*)(wih1b + (size_t)row0 * 1024 + (cc << 4));
  const uint4* wpB = (const uint4*)(wih1b + (size_t)(row0 + 1) * 1024 + (cc << 4));
  uint4 wA0 = wpA[0], wA1 = wpA[1];
  uint4 wB0 = wpB[0], wB1 = wpB[1];

  float* zbase = z1r + (size_t)(c & 1) * 524288;
  for (int sl = 0; sl < 128; ++sl) {
    const int s = c * 128 + sl;
    const float4* hb4 = (const float4*)(h1r + (size_t)(s & 511) * 1024 + (cc << 4));
    float4 a0 = hb4[0], a1 = hb4[1], a2 = hb4[2], a3 = hb4[3];
    float aA = 0.0f, aB = 0.0f;
    mac8(aA, wA0, a0.x,a0.y,a0.z,a0.w, a1.x,a1.y,a1.z,a1.w);
    mac8(aA, wA1, a2.x,a2.y,a2.z,a2.w, a3.x,a3.y,a3.z,a3.w);
    mac8(aB, wB0, a0.x,a0.y,a0.z,a0.w, a1.x,a1.y,a1.z,a1.w);
    mac8(aB, wB1, a2.x,a2.y,a2.z,a2.w, a3.x,a3.y,a3.z,a3.w);
    #pragma unroll
    for (int m = 1; m < 64; m <<= 1) {
      aA += __shfl_xor(aA, m);
      aB += __shfl_xor(aB, m);
    }
    if (cc == 0) {
      zbase[(size_t)sl * 4096 + row0]     = aA;
      zbase[(size_t)sl * 4096 + row0 + 1] = aB;
    }
  }
}

// ---------------- per-step kernel: node t = L0 step t + L1 step t-DLAG ----------------
// 512 WGs x 256 thr (2 WG/CU). Blocks 0..255: layer0 step t (4 units/block, wave =
// 1 unit; h1 self-loop via 512-deep ring). Blocks 256..511: layer1 step s=t-DLAG
// (wave = 1 unit; streams ONLY Whh1 — Wih1*h1 comes precomputed from the z1 ring).
// Kernel boundary = global release/acquire; all reads target strictly-earlier nodes.
extern "C" __global__ void __launch_bounds__(256)
lstm_step(int t, const float* __restrict__ quote, char* __restrict__ ws)
{
  const unsigned short* whh0b = (const unsigned short*)(ws + WO_WHH0);
  const unsigned short* wih0b = (const unsigned short*)(ws + WO_WIH0);
  const unsigned short* whh1b = (const unsigned short*)(ws + WO_WHH1);
  const float* b0 = (const float*)(ws + WO_B0);
  const float* b1 = (const float*)(ws + WO_B1);
  float* h1r   = (float*)(ws + WO_H1R);
  float* z1r   = (float*)(ws + WO_Z1R);
  float* h2buf = (float*)(ws + WO_H2);
  float* cst0  = (float*)(ws + WO_CST0);
  float* cst1  = (float*)(ws + WO_CST1);

  const int tid = threadIdx.x;
  const int wv  = tid >> 6;          // 0..3
  const int c   = tid & 63;

  float acc[4];
  #pragma unroll
  for (int i = 0; i < 4; ++i) acc[i] = 0.0f;

  if (blockIdx.x < 256) {
    // ========================= layer 0, step t =========================
    if (t >= T_SEQ) return;
    const int u = (int)blockIdx.x * 4 + wv;        // this wave's unit

    float hv[16];
    if (t > 0) {                                   // h1[t-1] from ring (float4)
      const float4* hb4 = (const float4*)(h1r + (size_t)((t - 1) & 511) * 1024 + (c << 4));
      float4 a0 = hb4[0], a1 = hb4[1], a2 = hb4[2], a3 = hb4[3];
      hv[0]=a0.x; hv[1]=a0.y; hv[2]=a0.z; hv[3]=a0.w;
      hv[4]=a1.x; hv[5]=a1.y; hv[6]=a1.z; hv[7]=a1.w;
      hv[8]=a2.x; hv[9]=a2.y; hv[10]=a2.z; hv[11]=a2.w;
      hv[12]=a3.x; hv[13]=a3.y; hv[14]=a3.z; hv[15]=a3.w;
    }
    if (c < 38) {                                  // x-part (independent work)
      float xv[8];
      int x0 = c << 3;
      const float* xr = quote + (size_t)t * 300;
      #pragma unroll
      for (int m = 0; m < 8; ++m) xv[m] = (x0 + m < 300) ? xr[x0 + m] : 0.0f;
      #pragma unroll
      for (int g = 0; g < 4; ++g) {
        int row = (g << 10) + u;
        uint4 w = *(const uint4*)(wih0b + (size_t)row * 304 + (c << 3));
        mac8(acc[g], w, xv[0],xv[1],xv[2],xv[3],xv[4],xv[5],xv[6],xv[7]);
      }
    }
    if (t > 0) {                                   // h-part
      #pragma unroll
      for (int g = 0; g < 4; ++g) {
        int row = (g << 10) + u;
        const uint4* wp = (const uint4*)(whh0b + (size_t)row * 1024 + (c << 4));
        uint4 w0 = wp[0], w1 = wp[1];
        mac8(acc[g], w0, hv[0],hv[1],hv[2],hv[3],hv[4],hv[5],hv[6],hv[7]);
        mac8(acc[g], w1, hv[8],hv[9],hv[10],hv[11],hv[12],hv[13],hv[14],hv[15]);
      }
    }
    #pragma unroll
    for (int i = 0; i < 4; ++i) {                  // full butterfly
      #pragma unroll
      for (int m = 1; m < 64; m <<= 1) acc[i] += __shfl_xor(acc[i], m);
    }
    if (c == 0) {                                  // gates + state update
      float pre[4];
      #pragma unroll
      for (int g = 0; g < 4; ++g) pre[g] = acc[g] + b0[(g << 10) + u];
      float ig = 1.0f/(1.0f+expf(-pre[0])), fg = 1.0f/(1.0f+expf(-pre[1]));
      float gg = tanhf(pre[2]),             og = 1.0f/(1.0f+expf(-pre[3]));
      float cs = fg * cst0[u] + ig * gg;
      cst0[u] = cs;
      h1r[(size_t)(t & 511) * 1024 + u] = og * tanhf(cs);
    }
  } else {
    // ========================= layer 1, step s = t - DLAG =========================
    const int s = t - DLAG;
    if (s < 0 || s >= T_SEQ) return;
    const int u = ((int)blockIdx.x - 256) * 4 + wv;

    // z1[s] from chunk ring (4 broadcast scalar loads; chunk GEMM ran >= 4 nodes ago)
    const float* zb = z1r + (size_t)((s >> 7) & 1) * 524288 + (size_t)(s & 127) * 4096;
    float zv[4];
    #pragma unroll
    for (int g = 0; g < 4; ++g) zv[g] = zb[(g << 10) + u];

    if (s > 0) {                                   // Whh1 * h2[s-1]
      const float4* hb4 = (const float4*)(h2buf + (size_t)((s - 1) & 1) * 1024 + (c << 4));
      float4 a0 = hb4[0], a1 = hb4[1], a2 = hb4[2], a3 = hb4[3];
      float hv[16] = {a0.x,a0.y,a0.z,a0.w, a1.x,a1.y,a1.z,a1.w,
                      a2.x,a2.y,a2.z,a2.w, a3.x,a3.y,a3.z,a3.w};
      #pragma unroll
      for (int g = 0; g < 4; ++g) {
        int row = (g << 10) + u;
        const uint4* wp = (const uint4*)(whh1b + (size_t)row * 1024 + (c << 4));
        uint4 w0 = wp[0], w1 = wp[1];
        mac8(acc[g], w0, hv[0],hv[1],hv[2],hv[3],hv[4],hv[5],hv[6],hv[7]);
        mac8(acc[g], w1, hv[8],hv[9],hv[10],hv[11],hv[12],hv[13],hv[14],hv[15]);
      }
    }
    #pragma unroll
    for (int i = 0; i < 4; ++i) {
      #pragma unroll
      for (int m = 1; m < 64; m <<= 1) acc[i] += __shfl_xor(acc[i], m);
    }
    if (c == 0) {
      float pre[4];
      #pragma unroll
      for (int g = 0; g < 4; ++g) pre[g] = acc[g] + zv[g] + b1[(g << 10) + u];
      float ig = 1.0f/(1.0f+expf(-pre[0])), fg = 1.0f/(1.0f+expf(-pre[1]));
      float gg = tanhf(pre[2]),             og = 1.0f/(1.0f+expf(-pre[3]));
      float cs = fg * cst1[u] + ig * gg;
      cst1[u] = cs;
      h2buf[(size_t)(s & 1) * 1024 + u] = og * tanhf(cs);
    }
  }
}

// ---------------- tiny MLP head ----------------
extern "C" __global__ void __launch_bounds__(256)
head_fc(const float* __restrict__ W, const float* __restrict__ b,
        const float* __restrict__ xin, float* __restrict__ y, int n_in)
{
  __shared__ float sred[256];
  const int i = blockIdx.x;
  float p = 0.0f;
  for (int k = threadIdx.x; k < n_in; k += 256)
    p = fmaf(W[(size_t)i * n_in + k], xin[k], p);
  sred[threadIdx.x] = p;
  __syncthreads();
  for (int s = 128; s > 0; s >>= 1) {
    if (threadIdx.x < s) sred[threadIdx.x] += sred[threadIdx.x + s];
    __syncthreads();
  }
  if (threadIdx.x == 0) y[i] = fmaxf(sred[0] + b[i], 0.0f);
}

extern "C" __global__ void __launch_bounds__(64)
head_out(const float* __restrict__ W2, const float* __restrict__ b2,
         const float* __restrict__ y1, float* __restrict__ out)
{
  const int l = threadIdx.x;
  float p0 = 0.0f, p1 = 0.0f, p2 = 0.0f;
  for (int k = l; k < 512; k += 64) {
    float v = y1[k];
    p0 = fmaf(W2[k],        v, p0);
    p1 = fmaf(W2[512 + k],  v, p1);
    p2 = fmaf(W2[1024 + k], v, p2);
  }
  #pragma unroll
  for (int m = 1; m < 64; m <<= 1) {
    p0 += __shfl_xor(p0, m);
    p1 += __shfl_xor(p1, m);
    p2 += __shfl_xor(p2, m);
  }
  if (l == 0) {
    float z0 = p0 + b2[0], z1 = p1 + b2[1], z2 = p2 + b2[2];
    float mx = fmaxf(z0, fmaxf(z1, z2));
    float lse = mx + logf(expf(z0 - mx) + expf(z1 - mx) + expf(z2 - mx));
    out[0] = z0 - lse; out[1] = z1 - lse; out[2] = z2 - lse;
  }
}

// ---------------- host ----------------
extern "C" void kernel_launch(void* const* d_in, const int* in_sizes, int n_in,
                              void* d_out, int out_size, void* d_ws, size_t ws_size,
                              hipStream_t stream)
{
  (void)in_sizes; (void)n_in; (void)out_size; (void)ws_size;
  const float* quote = (const float*)d_in[0];
  const float* Wih0  = (const float*)d_in[1];
  const float* Whh0  = (const float*)d_in[2];
  const float* bih0  = (const float*)d_in[3];
  const float* bhh0  = (const float*)d_in[4];
  const float* Wih1  = (const float*)d_in[5];
  const float* Whh1  = (const float*)d_in[6];
  const float* bih1  = (const float*)d_in[7];
  const float* bhh1  = (const float*)d_in[8];
  const float* W0    = (const float*)d_in[9];
  const float* b0    = (const float*)d_in[10];
  const float* W1    = (const float*)d_in[11];
  const float* b1    = (const float*)d_in[12];
  const float* W2    = (const float*)d_in[13];
  const float* b2    = (const float*)d_in[14];

  char* ws = (char*)d_ws;
  float* h2buf = (float*)(ws + WO_H2);
  float* y0    = (float*)(ws + WO_Y0);
  float* y1    = (float*)(ws + WO_Y1);

  // cell states must be zero at every call start
  hipMemsetAsync(ws + WO_CST0, 0, 8192, stream);

  prep_weights<<<2048, 256, 0, stream>>>(Wih0, Whh0, bih0, bhh0,
                                         Wih1, Whh1, bih1, bhh1, ws);

  // node t: L0 step t + L1 step t-DLAG; after every 128th L0 step, a GEMM node
  // precomputes that chunk's z1 = Wih1*h1 (consumed by L1 >= 4 nodes later).
  for (int t = 0; t <= T_SEQ - 1 + DLAG; ++t) {
    lstm_step<<<512, 256, 0, stream>>>(t, quote, ws);
    if (t < T_SEQ && ((t + 1) & 127) == 0)
      gemm_z1<<<512, 256, 0, stream>>>((t + 1) / 128 - 1, ws);
  }

  // h2[T-1] is at parity (8191 & 1) = 1
  head_fc<<<512, 256, 0, stream>>>(W0, b0, h2buf + 1024, y0, 1024);
  head_fc<<<512, 256, 0, stream>>>(W1, b1, y0, y1, 512);
  head_out<<<1, 64, 0, stream>>>(W2, b2, y1, (float*)d_out);
}

// Round 15
// 42251.047 us; speedup vs baseline: 1.1580x; 1.1580x over previous
//
#include <hip/hip_runtime.h>
#include <stdint.h>

typedef unsigned int uint32;
typedef unsigned long long uint64;

#define T_SEQ 8192

// ---------------- ws layout (~27.7MB) ----------------
#define WO_WHH0  0ull          // [4096][1024] bf16
#define WO_WIH0  8388608ull    // [4096][304]  bf16 (300 padded to 304)
#define WO_WHH1  10878976ull   // [4096][1024] bf16
#define WO_WIH1  19267584ull   // [4096][1024] bf16
#define WO_B0    27656192ull   // [4096] f32  (bih0+bhh0)
#define WO_B1    27672576ull   // [4096] f32
#define WO_H1    27688960ull   // [2][1024] f32 (parity t&1)
#define WO_H2    27697152ull   // [2][1024] f32 (parity s&1)
#define WO_CST0  27705344ull   // [1024] f32
#define WO_CST1  27709440ull   // [1024] f32
#define WO_Y0    27713536ull   // [512] f32
#define WO_Y1    27715584ull   // [512] f32

// ---------------- helpers ----------------
__device__ __forceinline__ float bflo(uint32 u){ return __uint_as_float(u << 16); }
__device__ __forceinline__ float bfhi(uint32 u){ return __uint_as_float(u & 0xffff0000u); }

__device__ __forceinline__ unsigned short f2bf(float f){
  uint32 u = __float_as_uint(f);
  u += 0x7fffu + ((u >> 16) & 1u);          // round-to-nearest-even
  return (unsigned short)(u >> 16);
}

__device__ __forceinline__ void mac8(float& a, uint4 w,
    float h0,float h1,float h2,float h3,float h4,float h5,float h6,float h7){
  a = fmaf(bflo(w.x), h0, a); a = fmaf(bfhi(w.x), h1, a);
  a = fmaf(bflo(w.y), h2, a); a = fmaf(bfhi(w.y), h3, a);
  a = fmaf(bflo(w.z), h4, a); a = fmaf(bfhi(w.z), h5, a);
  a = fmaf(bflo(w.w), h6, a); a = fmaf(bfhi(w.w), h7, a);
}

// ---------------- one-time per call: weights fp32 -> bf16 + bias sums ----------------
extern "C" __global__ void __launch_bounds__(256)
prep_weights(const float* __restrict__ Wih0, const float* __restrict__ Whh0,
             const float* __restrict__ bih0, const float* __restrict__ bhh0,
             const float* __restrict__ Wih1, const float* __restrict__ Whh1,
             const float* __restrict__ bih1, const float* __restrict__ bhh1,
             char* __restrict__ ws)
{
  unsigned short* whh0b = (unsigned short*)(ws + WO_WHH0);
  unsigned short* wih0b = (unsigned short*)(ws + WO_WIH0);
  unsigned short* whh1b = (unsigned short*)(ws + WO_WHH1);
  unsigned short* wih1b = (unsigned short*)(ws + WO_WIH1);
  float* b0 = (float*)(ws + WO_B0);
  float* b1 = (float*)(ws + WO_B1);

  const int stride = gridDim.x * blockDim.x;
  const int tid0 = blockIdx.x * blockDim.x + threadIdx.x;

  for (int i = tid0; i < 4096*1024; i += stride) whh0b[i] = f2bf(Whh0[i]);
  for (int i = tid0; i < 4096*1024; i += stride) whh1b[i] = f2bf(Whh1[i]);
  for (int i = tid0; i < 4096*1024; i += stride) wih1b[i] = f2bf(Wih1[i]);
  for (int i = tid0; i < 4096*304;  i += stride) {
    int r = i / 304, x = i - r * 304;
    wih0b[i] = f2bf(x < 300 ? Wih0[(size_t)r * 300 + x] : 0.0f);
  }
  for (int i = tid0; i < 4096; i += stride) {
    b0[i] = bih0[i] + bhh0[i];
    b1[i] = bih1[i] + bhh1[i];
  }
}

// ---------------- per-step kernel: node t = L0 step t + L1 step t-1 ----------------
// 512 WGs x 256 thr (2 WG/CU, 8 waves/CU). Blocks 0..255: layer0 step t; blocks
// 256..511: layer1 step t-1. Each WG owns 4 units; wave wv owns ONE unit
// (4 gate rows x 1024 cols = 8KB bf16). All state in ws via PLAIN loads/stores —
// the kernel boundary is the global release/acquire (no polls, no atomics).
// Full 64-lane butterfly -> lane 0 holds all 4 gate sums -> gates + state update.
// [R13/R14 ablations: per-wave load balance and -8MB/step weight stream are both
//  neutral -> nodes are dispatch-gap-bound (~5us); weights are L2-resident.]
extern "C" __global__ void __launch_bounds__(256)
lstm_step(int t, const float* __restrict__ quote, char* __restrict__ ws)
{
  const unsigned short* whh0b = (const unsigned short*)(ws + WO_WHH0);
  const unsigned short* wih0b = (const unsigned short*)(ws + WO_WIH0);
  const unsigned short* whh1b = (const unsigned short*)(ws + WO_WHH1);
  const unsigned short* wih1b = (const unsigned short*)(ws + WO_WIH1);
  const float* b0 = (const float*)(ws + WO_B0);
  const float* b1 = (const float*)(ws + WO_B1);
  float* h1buf = (float*)(ws + WO_H1);
  float* h2buf = (float*)(ws + WO_H2);
  float* cst0  = (float*)(ws + WO_CST0);
  float* cst1  = (float*)(ws + WO_CST1);

  const int tid = threadIdx.x;
  const int wv  = tid >> 6;          // 0..3
  const int c   = tid & 63;

  float acc[4];
  #pragma unroll
  for (int i = 0; i < 4; ++i) acc[i] = 0.0f;

  if (blockIdx.x < 256) {
    // ========================= layer 0, step t =========================
    if (t >= T_SEQ) return;
    const int u = (int)blockIdx.x * 4 + wv;        // this wave's unit

    if (c < 38) {                                  // x-part
      float xv[8];
      int x0 = c << 3;
      const float* xr = quote + (size_t)t * 300;
      #pragma unroll
      for (int m = 0; m < 8; ++m) xv[m] = (x0 + m < 300) ? xr[x0 + m] : 0.0f;
      #pragma unroll
      for (int g = 0; g < 4; ++g) {
        int row = (g << 10) + u;
        uint4 w = *(const uint4*)(wih0b + (size_t)row * 304 + (c << 3));
        mac8(acc[g], w, xv[0],xv[1],xv[2],xv[3],xv[4],xv[5],xv[6],xv[7]);
      }
    }
    if (t > 0) {                                   // h-part: h1[t-1]
      const float* hb = h1buf + (size_t)((t - 1) & 1) * 1024;
      float hv[16];
      #pragma unroll
      for (int k = 0; k < 16; ++k) hv[k] = hb[(c << 4) + k];
      #pragma unroll
      for (int g = 0; g < 4; ++g) {
        int row = (g << 10) + u;
        const uint4* wp = (const uint4*)(whh0b + (size_t)row * 1024 + (c << 4));
        uint4 w0 = wp[0], w1 = wp[1];
        mac8(acc[g], w0, hv[0],hv[1],hv[2],hv[3],hv[4],hv[5],hv[6],hv[7]);
        mac8(acc[g], w1, hv[8],hv[9],hv[10],hv[11],hv[12],hv[13],hv[14],hv[15]);
      }
    }
    #pragma unroll
    for (int i = 0; i < 4; ++i) {                  // full butterfly
      #pragma unroll
      for (int m = 1; m < 64; m <<= 1) acc[i] += __shfl_xor(acc[i], m);
    }
    if (c == 0) {                                  // gates + state update
      float pre[4];
      #pragma unroll
      for (int g = 0; g < 4; ++g) pre[g] = acc[g] + b0[(g << 10) + u];
      float ig = 1.0f/(1.0f+expf(-pre[0])), fg = 1.0f/(1.0f+expf(-pre[1]));
      float gg = tanhf(pre[2]),             og = 1.0f/(1.0f+expf(-pre[3]));
      float cs = fg * cst0[u] + ig * gg;
      cst0[u] = cs;
      h1buf[(size_t)(t & 1) * 1024 + u] = og * tanhf(cs);
    }
  } else {
    // ========================= layer 1, step s = t-1 =========================
    const int s = t - 1;
    if (s < 0) return;
    const int u = ((int)blockIdx.x - 256) * 4 + wv;

    {                                              // Wih1 * h1[s]
      const float* hb = h1buf + (size_t)(s & 1) * 1024;
      float hv[16];
      #pragma unroll
      for (int k = 0; k < 16; ++k) hv[k] = hb[(c << 4) + k];
      #pragma unroll
      for (int g = 0; g < 4; ++g) {
        int row = (g << 10) + u;
        const uint4* wp = (const uint4*)(wih1b + (size_t)row * 1024 + (c << 4));
        uint4 w0 = wp[0], w1 = wp[1];
        mac8(acc[g], w0, hv[0],hv[1],hv[2],hv[3],hv[4],hv[5],hv[6],hv[7]);
        mac8(acc[g], w1, hv[8],hv[9],hv[10],hv[11],hv[12],hv[13],hv[14],hv[15]);
      }
    }
    if (s > 0) {                                   // Whh1 * h2[s-1]
      const float* hb = h2buf + (size_t)((s - 1) & 1) * 1024;
      float hv[16];
      #pragma unroll
      for (int k = 0; k < 16; ++k) hv[k] = hb[(c << 4) + k];
      #pragma unroll
      for (int g = 0; g < 4; ++g) {
        int row = (g << 10) + u;
        const uint4* wp = (const uint4*)(whh1b + (size_t)row * 1024 + (c << 4));
        uint4 w0 = wp[0], w1 = wp[1];
        mac8(acc[g], w0, hv[0],hv[1],hv[2],hv[3],hv[4],hv[5],hv[6],hv[7]);
        mac8(acc[g], w1, hv[8],hv[9],hv[10],hv[11],hv[12],hv[13],hv[14],hv[15]);
      }
    }
    #pragma unroll
    for (int i = 0; i < 4; ++i) {
      #pragma unroll
      for (int m = 1; m < 64; m <<= 1) acc[i] += __shfl_xor(acc[i], m);
    }
    if (c == 0) {
      float pre[4];
      #pragma unroll
      for (int g = 0; g < 4; ++g) pre[g] = acc[g] + b1[(g << 10) + u];
      float ig = 1.0f/(1.0f+expf(-pre[0])), fg = 1.0f/(1.0f+expf(-pre[1]));
      float gg = tanhf(pre[2]),             og = 1.0f/(1.0f+expf(-pre[3]));
      float cs = fg * cst1[u] + ig * gg;
      cst1[u] = cs;
      h2buf[(size_t)(s & 1) * 1024 + u] = og * tanhf(cs);
    }
  }
}

// ---------------- tiny MLP head ----------------
extern "C" __global__ void __launch_bounds__(256)
head_fc(const float* __restrict__ W, const float* __restrict__ b,
        const float* __restrict__ xin, float* __restrict__ y, int n_in)
{
  __shared__ float sred[256];
  const int i = blockIdx.x;
  float p = 0.0f;
  for (int k = threadIdx.x; k < n_in; k += 256)
    p = fmaf(W[(size_t)i * n_in + k], xin[k], p);
  sred[threadIdx.x] = p;
  __syncthreads();
  for (int s = 128; s > 0; s >>= 1) {
    if (threadIdx.x < s) sred[threadIdx.x] += sred[threadIdx.x + s];
    __syncthreads();
  }
  if (threadIdx.x == 0) y[i] = fmaxf(sred[0] + b[i], 0.0f);
}

extern "C" __global__ void __launch_bounds__(64)
head_out(const float* __restrict__ W2, const float* __restrict__ b2,
         const float* __restrict__ y1, float* __restrict__ out)
{
  const int l = threadIdx.x;
  float p0 = 0.0f, p1 = 0.0f, p2 = 0.0f;
  for (int k = l; k < 512; k += 64) {
    float v = y1[k];
    p0 = fmaf(W2[k],        v, p0);
    p1 = fmaf(W2[512 + k],  v, p1);
    p2 = fmaf(W2[1024 + k], v, p2);
  }
  #pragma unroll
  for (int m = 1; m < 64; m <<= 1) {
    p0 += __shfl_xor(p0, m);
    p1 += __shfl_xor(p1, m);
    p2 += __shfl_xor(p2, m);
  }
  if (l == 0) {
    float z0 = p0 + b2[0], z1 = p1 + b2[1], z2 = p2 + b2[2];
    float mx = fmaxf(z0, fmaxf(z1, z2));
    float lse = mx + logf(expf(z0 - mx) + expf(z1 - mx) + expf(z2 - mx));
    out[0] = z0 - lse; out[1] = z1 - lse; out[2] = z2 - lse;
  }
}

// ---------------- host ----------------
extern "C" void kernel_launch(void* const* d_in, const int* in_sizes, int n_in,
                              void* d_out, int out_size, void* d_ws, size_t ws_size,
                              hipStream_t stream)
{
  (void)in_sizes; (void)n_in; (void)out_size; (void)ws_size;
  const float* quote = (const float*)d_in[0];
  const float* Wih0  = (const float*)d_in[1];
  const float* Whh0  = (const float*)d_in[2];
  const float* bih0  = (const float*)d_in[3];
  const float* bhh0  = (const float*)d_in[4];
  const float* Wih1  = (const float*)d_in[5];
  const float* Whh1  = (const float*)d_in[6];
  const float* bih1  = (const float*)d_in[7];
  const float* bhh1  = (const float*)d_in[8];
  const float* W0    = (const float*)d_in[9];
  const float* b0    = (const float*)d_in[10];
  const float* W1    = (const float*)d_in[11];
  const float* b1    = (const float*)d_in[12];
  const float* W2    = (const float*)d_in[13];
  const float* b2    = (const float*)d_in[14];

  char* ws = (char*)d_ws;
  float* h2buf = (float*)(ws + WO_H2);
  float* y0    = (float*)(ws + WO_Y0);
  float* y1    = (float*)(ws + WO_Y1);

  // cell states must be zero at every call start
  hipMemsetAsync(ws + WO_CST0, 0, 8192, stream);

  prep_weights<<<2048, 256, 0, stream>>>(Wih0, Whh0, bih0, bhh0,
                                         Wih1, Whh1, bih1, bhh1, ws);

  // node t: L0 step t (blocks 0..255) + L1 step t-1 (blocks 256..511)
  for (int t = 0; t <= T_SEQ; ++t)
    lstm_step<<<512, 256, 0, stream>>>(t, quote, ws);

  // h2[T-1] is at parity (8191 & 1) = 1
  head_fc<<<512, 256, 0, stream>>>(W0, b0, h2buf + 1024, y0, 1024);
  head_fc<<<512, 256, 0, stream>>>(W1, b1, y0, y1, 512);
  head_out<<<1, 64, 0, stream>>>(W2, b2, y1, (float*)d_out);
}